// Round 9
// baseline (67.077 us; speedup 1.0000x reference)
//
#include <hip/hip_runtime.h>

#define SS 2704                // 52*52
#define NA 5
#define NC 20
#define NB 128
#define CELLS (NB * SS)        // 346112
#define TILE 64                // cells per tile
#define TPT 4                  // tiles per block
#define BCELLS (TILE * TPT)    // 256 cells per block
#define TPB 320                // 5 waves; wave index == anchor index
#define NBLK (CELLS / BCELLS)  // 1352 exactly
#define RBLOCK 1024

__device__ __forceinline__ float fast_sigmoid(float x) {
    return __builtin_amdgcn_rcpf(1.0f + __expf(-x));
}
__device__ __forceinline__ float fast_softplus(float x) {
    // logaddexp(0,x) = max(x,0) + log(1 + exp(-|x|)); all HW instrs
    return fmaxf(x, 0.0f) + __logf(1.0f + __expf(-fabsf(x)));
}

// block = 4x64-cell tiles; wave = anchor; lane = cell-in-tile.
// All 4 flag + 4 conf loads issued up front (independent, in flight together)
// -> 4 interleaved dependent chains per wave instead of 1 (latency hiding via
// ILP; no LDS, no barriers). Class loss stays wave-compacted via ballot.
__global__ __launch_bounds__(TPB) void yolo_main(
        const float* __restrict__ P,      // (B, 125, S, S)
        const float* __restrict__ T,      // (B, S, S, 5, 25)
        const float* __restrict__ anch,   // (5, 2)
        float* __restrict__ partial) {
    __shared__ float red[NA][4];

    int a    = threadIdx.x >> 6;          // 0..4, wave-uniform
    int lane = threadIdx.x & 63;
    int base = blockIdx.x * BCELLS;
    float aw  = anch[2 * a];
    float ahv = anch[2 * a + 1];

    // ---- per-tile geometry (compile-time indexed arrays -> registers) ----
    int cellv[TPT], bv[TPT], ijv[TPT];
    #pragma unroll
    for (int t = 0; t < TPT; ++t) {
        cellv[t] = base + t * TILE + lane;
        bv[t]    = cellv[t] / SS;
        ijv[t]   = cellv[t] - bv[t] * SS;
    }

    // ---- issue ALL flag + conf loads up front (8 independent loads) ----
    float fl[TPT], cf[TPT];
    #pragma unroll
    for (int t = 0; t < TPT; ++t)
        fl[t] = T[(size_t)cellv[t] * 125 + a * 25 + 4];
    #pragma unroll
    for (int t = 0; t < TPT; ++t)
        cf[t] = P[((size_t)bv[t] * 125 + a * 25 + 4) * SS + ijv[t]];

    float s_xywh = 0.0f, s_cls = 0.0f, s_obj = 0.0f, s_noobj = 0.0f;

    #pragma unroll
    for (int t = 0; t < TPT; ++t) {
        const float* Ta = T + (size_t)cellv[t] * 125 + a * 25;
        const float* Pa = P + ((size_t)bv[t] * 125 + a * 25) * SS + ijv[t];
        float cp = fast_sigmoid(cf[t]);
        bool isobj = (fl[t] != 0.0f);

        if (isobj) {
            float tx = Pa[0], ty = Pa[SS], tw = Pa[2 * SS], th = Pa[3 * SS];
            float gx = Ta[0], gy = Ta[1], gw = Ta[2], gh = Ta[3];
            float cx = fast_sigmoid(tx), cy = fast_sigmoid(ty);
            float pw = __expf(tw) * aw;
            float ph = __expf(th) * ahv;
            // IoU invariant to common (+j,+i) shift -> dropped.
            float iw = fmaxf(fminf(gx + 0.5f * gw, cx + 0.5f * pw) -
                             fmaxf(gx - 0.5f * gw, cx - 0.5f * pw), 0.0f);
            float ih = fmaxf(fminf(gy + 0.5f * gh, cy + 0.5f * ph) -
                             fmaxf(gy - 0.5f * gh, cy - 0.5f * ph), 0.0f);
            float inter = iw * ih;
            float uni   = gw * gh + pw * ph - inter;
            float iou   = (uni > 0.0f) ? inter * __builtin_amdgcn_rcpf(uni) : 0.0f;

            float dx = cx - gx, dy = cy - gy;
            s_xywh += dx * dx + dy * dy;
            const float eps = 1e-6f;
            float dw = __fsqrt_rn(pw + eps) - __fsqrt_rn(gw + eps);
            float dh = __fsqrt_rn(ph + eps) - __fsqrt_rn(gh + eps);
            s_xywh += dw * dw + dh * dh;

            float dob = iou - cp;
            s_obj += dob * dob;
        } else {
            s_noobj += cp * cp;
        }

        // ---- wave-compacted class loss for this tile ----
        unsigned long long act = __ballot(isobj);     // wave-uniform
        int nact = __popcll(act);
        int slot_off = lane / 20;                     // 0,1,2 (lanes 60-63 idle)
        int c = lane - slot_off * 20;                 // class index 0..19
        unsigned long long m = act;
        for (int basep = 0; basep < nact; basep += 3) {
            unsigned long long m0 = m;
            unsigned long long m1 = m0 & (m0 - 1);
            unsigned long long m2 = m1 & (m1 - 1);
            int src0 = __ffsll(m0) - 1;
            int src1 = __ffsll(m1) - 1;
            int src2 = __ffsll(m2) - 1;
            m = m2 & (m2 - 1);

            int s   = basep + slot_off;
            int src = (slot_off == 0) ? src0 : (slot_off == 1) ? src1 : src2;
            if (slot_off < 3 && s < nact) {
                int pcell = base + t * TILE + src;
                int pb    = pcell / SS;
                int pij   = pcell - pb * SS;
                float tt = T[(size_t)pcell * 125 + a * 25 + 5 + c];
                float l  = P[((size_t)pb * 125 + a * 25 + 5 + c) * SS + pij];
                s_cls += fast_softplus(l) - l * tt;
            }
        }
    }

    // ---- wave reduce (64 lanes), then cross-wave via tiny LDS ----
    #pragma unroll
    for (int off = 32; off > 0; off >>= 1) {
        s_xywh  += __shfl_xor(s_xywh,  off, 64);
        s_cls   += __shfl_xor(s_cls,   off, 64);
        s_obj   += __shfl_xor(s_obj,   off, 64);
        s_noobj += __shfl_xor(s_noobj, off, 64);
    }
    if (lane == 0) {
        red[a][0] = s_xywh; red[a][1] = s_cls; red[a][2] = s_obj; red[a][3] = s_noobj;
    }
    __syncthreads();
    if (threadIdx.x == 0) {
        float r0 = 0, r1 = 0, r2 = 0, r3 = 0;
        #pragma unroll
        for (int w = 0; w < NA; ++w) {
            r0 += red[w][0]; r1 += red[w][1]; r2 += red[w][2]; r3 += red[w][3];
        }
        float* p = partial + (size_t)blockIdx.x * 4;
        p[0] = r0; p[1] = r1; p[2] = r2; p[3] = r3;
    }
}

__global__ __launch_bounds__(RBLOCK) void yolo_reduce(
        const float* __restrict__ partial, int n, float* __restrict__ out) {
    float v0 = 0.0f, v1 = 0.0f, v2 = 0.0f, v3 = 0.0f;
    for (int i = threadIdx.x; i < n; i += RBLOCK) {
        const float* p = partial + (size_t)i * 4;
        v0 += p[0]; v1 += p[1]; v2 += p[2]; v3 += p[3];
    }
    #pragma unroll
    for (int off = 32; off > 0; off >>= 1) {
        v0 += __shfl_xor(v0, off, 64);
        v1 += __shfl_xor(v1, off, 64);
        v2 += __shfl_xor(v2, off, 64);
        v3 += __shfl_xor(v3, off, 64);
    }
    __shared__ float red[RBLOCK / 64][4];
    int wid = threadIdx.x >> 6, lane = threadIdx.x & 63;
    if (lane == 0) {
        red[wid][0] = v0; red[wid][1] = v1; red[wid][2] = v2; red[wid][3] = v3;
    }
    __syncthreads();
    if (threadIdx.x == 0) {
        float xywh = 0, cls = 0, obj = 0, noobj = 0;
        #pragma unroll
        for (int q = 0; q < RBLOCK / 64; ++q) {
            xywh += red[q][0]; cls += red[q][1]; obj += red[q][2]; noobj += red[q][3];
        }
        out[0] = 5.0f * xywh + 5.0f * obj + 0.5f * noobj + cls;
        out[1] = xywh;
        out[2] = cls;
        out[3] = obj + noobj;
    }
}

extern "C" void kernel_launch(void* const* d_in, const int* in_sizes, int n_in,
                              void* d_out, int out_size, void* d_ws, size_t ws_size,
                              hipStream_t stream) {
    const float* P = (const float*)d_in[0];
    const float* T = (const float*)d_in[1];
    const float* anch = (const float*)d_in[2];
    float* out = (float*)d_out;
    float* partial = (float*)d_ws;   // NBLK * 4 floats = 21.6 KB

    yolo_main<<<NBLK, TPB, 0, stream>>>(P, T, anch, partial);
    yolo_reduce<<<1, RBLOCK, 0, stream>>>(partial, NBLK, out);
}